// Round 8
// baseline (23.373 us; speedup 1.0000x reference)
//
#include <hip/hip_runtime.h>

// SWT-Haar level-1 MSE loss == plain MSE(x, target).
// Identity: with d = x-t, dr = roll(d,-1):
//   (cA_x-cA_t)^2 + (cD_x-cD_t)^2 = 0.5[(d+dr)^2 + (dr-d)^2] = d^2 + dr^2,
//   sum(dr^2) == sum(d^2) (circular shift is a permutation per row),
//   so mean over the 2N stacked coeffs = sum(d^2)/N = MSE(x, t).
//
// Structure settled by R2-R7 measurements: plain two-kernel reduction wins.
//  - fused + agent-scope release/acquire: 131-178 us (per-block L2 wb/inv)
//  - fused + relaxed packed atomic (+memset node): 26-28 us
//  - two-kernel, no atomics, no reset: 23.25 us
// k1 is at the measured read ceiling (~6.3-6.9 TB/s -> ~16 us for 100.7 MB).
// R8 change: k2 slimmed to ONE wave (64 threads) -- no LDS, no barrier,
// fully unrolled 32 f64 loads/lane, butterfly reduce, one store.

typedef float v4f __attribute__((ext_vector_type(4)));

#define NBLOCKS 2048   // 8 blocks/CU x 256 CUs
#define NTHREADS 256
#define PAIRS 6        // n4 / (NBLOCKS*NTHREADS) for N = 16*3*512*512

__global__ __launch_bounds__(NTHREADS)
void swt_mse_partial(const v4f* __restrict__ x, const v4f* __restrict__ t,
                     double* __restrict__ part, int n4) {
    const int tid = blockIdx.x * NTHREADS + threadIdx.x;
    const int stride = NBLOCKS * NTHREADS;

    float acc = 0.0f;  // <=24 f32 terms/thread: accumulation error negligible
    if (n4 == PAIRS * stride) {
        // Exact-fit path: compile-time trip count, 12 independent dwordx4
        // loads pipelined by the compiler.
        #pragma unroll
        for (int k = 0; k < PAIRS; ++k) {
            v4f a = x[tid + k * stride];
            v4f b = t[tid + k * stride];
            v4f d = a - b;
            acc += d.x * d.x + d.y * d.y + d.z * d.z + d.w * d.w;
        }
    } else {
        for (int i = tid; i < n4; i += stride) {
            v4f a = x[i], b = t[i];
            v4f d = a - b;
            acc += d.x * d.x + d.y * d.y + d.z * d.z + d.w * d.w;
        }
    }

    // wave64 butterfly reduce (double)
    double dacc = (double)acc;
    #pragma unroll
    for (int off = 32; off > 0; off >>= 1)
        dacc += __shfl_down(dacc, off, 64);

    __shared__ double sm[NTHREADS / 64];
    const int lane = threadIdx.x & 63;
    const int wid  = threadIdx.x >> 6;
    if (lane == 0) sm[wid] = dacc;
    __syncthreads();
    if (threadIdx.x == 0) {
        double s = 0.0;
        #pragma unroll
        for (int w = 0; w < NTHREADS / 64; ++w) s += sm[w];
        part[blockIdx.x] = s;  // every slot written every call -> deterministic
    }
}

// Single-wave finalizer: no LDS, no __syncthreads, minimal tail latency.
__global__ __launch_bounds__(64)
void swt_mse_final(const double* __restrict__ part, float* __restrict__ out,
                   double invN) {
    double acc = 0.0;
    // 2048 partials / 64 lanes = 32 per lane; fully unrolled so all loads
    // issue before the single waitcnt the compiler places at first use.
    #pragma unroll
    for (int k = 0; k < NBLOCKS / 64; ++k)
        acc += part[threadIdx.x + k * 64];
    #pragma unroll
    for (int off = 32; off > 0; off >>= 1)
        acc += __shfl_down(acc, off, 64);
    if (threadIdx.x == 0)
        out[0] = (float)(acc * invN);
}

extern "C" void kernel_launch(void* const* d_in, const int* in_sizes, int n_in,
                              void* d_out, int out_size, void* d_ws, size_t ws_size,
                              hipStream_t stream) {
    const float* x = (const float*)d_in[0];
    const float* t = (const float*)d_in[1];
    float* out = (float*)d_out;
    double* part = (double*)d_ws;  // 2048 * 8 B = 16 KB scratch

    long long N = (long long)in_sizes[0];   // 16*3*512*512 = 12,582,912
    int n4 = (int)(N / 4);                  // divisible by 4

    swt_mse_partial<<<NBLOCKS, NTHREADS, 0, stream>>>(
        (const v4f*)x, (const v4f*)t, part, n4);
    swt_mse_final<<<1, 64, 0, stream>>>(part, out, 1.0 / (double)N);
}